// Round 9
// baseline (433.399 us; speedup 1.0000x reference)
//
#include <hip/hip_runtime.h>
#include <hip/hip_cooperative_groups.h>
#include <math.h>

namespace cg = cooperative_groups;

#define N_NODES 100000
#define N_EDGES 800000
#define E_TOT (N_EDGES + N_NODES)
#define NEG_SLOPE 0.2f

typedef unsigned short ushort_t;
typedef __attribute__((ext_vector_type(8))) short short8v;   // 8 bf16
typedef __attribute__((ext_vector_type(4))) float f32x4;

static __device__ __forceinline__ float leaky(float e) {
  return e > 0.f ? e : NEG_SLOPE * e;
}

static __device__ __forceinline__ float b2f(ushort_t u) {
  union { unsigned int i; float f; } x;
  x.i = ((unsigned int)u) << 16;
  return x.f;
}

static __device__ __forceinline__ ushort_t f2b(float f) {
  union { float f; unsigned int i; } x;
  x.f = f;
  unsigned int r = x.i + 0x7FFFu + ((x.i >> 16) & 1u);  // RNE (finite inputs)
  return (ushort_t)(r >> 16);
}

// ---------------- cooperative CSR build + prep (replaces 5 dispatches) ----------------
// 256 blocks x 256 threads (1 block/CU, co-resident). Phases separated by
// grid.sync(): (0) zero deg/asrc1/adst1 + W transposes; (1) degree histogram;
// (2) two-level exclusive scan -> rowptr/fillpos; (3) edge fill.

__global__ __launch_bounds__(256) void csr_coop(
    const int* __restrict__ ei, int* __restrict__ deg,
    const float* __restrict__ W1, ushort_t* __restrict__ W1t,
    const float* __restrict__ W2, ushort_t* __restrict__ W2t,
    int* __restrict__ rowptr, int* __restrict__ fillpos,
    int* __restrict__ col, int* __restrict__ bsums,
    float* __restrict__ asrc1, float* __restrict__ adst1) {
  cg::grid_group grid = cg::this_grid();
  const int tid = threadIdx.x;
  const int bid = blockIdx.x;
  const int g = bid * 256 + tid;
  const int GT = 256 * 256;

  // phase 0: zeroing + weight transposes
  for (int i = g; i < N_NODES; i += GT) {
    deg[i] = 0; asrc1[i] = 0.f; adst1[i] = 0.f;
  }
  for (int i = g; i < 256 * 128; i += GT) {       // W1t[n][k] = W1[k][n]
    int n = i >> 7, k = i & 127;
    W1t[i] = f2b(W1[(size_t)k * 256 + n]);
  }
  for (int i = g; i < 64 * 256; i += GT) {        // W2t[n][k] = W2[k][n]
    int n = i >> 8, k = i & 255;
    W2t[i] = f2b(W2[(size_t)k * 64 + n]);
  }
  grid.sync();

  // phase 1: degree histogram
  for (int e = g; e < E_TOT; e += GT) {
    int d = (e < N_EDGES) ? ei[N_EDGES + e] : (e - N_EDGES);
    atomicAdd(&deg[d], 1);
  }
  grid.sync();

  // phase 2a: per-thread 2-element chunk; block scan of thread totals
  int i0 = g * 2;
  int d0 = (i0 < N_NODES) ? deg[i0] : 0;
  int d1 = (i0 + 1 < N_NODES) ? deg[i0 + 1] : 0;
  int ttot = d0 + d1;
  __shared__ int sh[256];
  sh[tid] = ttot;
  __syncthreads();
  for (int off = 1; off < 256; off <<= 1) {
    int t = (tid >= off) ? sh[tid - off] : 0;
    __syncthreads();
    sh[tid] += t;
    __syncthreads();
  }
  int tpre = sh[tid] - ttot;
  if (tid == 255) bsums[bid] = sh[255];
  grid.sync();

  // phase 2b: block offset = sum of bsums[0..bid-1]; write rowptr/fillpos
  __shared__ int boff_sh;
  if (tid < 64) {
    int p = 0;
#pragma unroll
    for (int k = 0; k < 4; ++k) {
      int idx = tid + k * 64;
      if (idx < bid) p += bsums[idx];
    }
#pragma unroll
    for (int o = 32; o; o >>= 1) p += __shfl_xor(p, o);
    if (tid == 0) boff_sh = p;
  }
  __syncthreads();
  int prefix = boff_sh + tpre;
  if (i0 < N_NODES) {
    rowptr[i0] = prefix; fillpos[i0] = prefix;
    if (i0 == N_NODES - 1) rowptr[N_NODES] = prefix + d0;
  }
  prefix += d0;
  if (i0 + 1 < N_NODES) {
    rowptr[i0 + 1] = prefix; fillpos[i0 + 1] = prefix;
    if (i0 + 1 == N_NODES - 1) rowptr[N_NODES] = prefix + d1;
  }
  grid.sync();

  // phase 3: edge fill
  for (int e = g; e < E_TOT; e += GT) {
    int s, d;
    if (e < N_EDGES) { s = ei[e]; d = ei[N_EDGES + e]; }
    else { s = d = e - N_EDGES; }
    int p = atomicAdd(&fillpos[d], 1);
    col[p] = s;
  }
}

// ---------------- MFMA GEMM with fused alpha epilogue ----------------
// ALPHA_MODE 1: per-row partial dots; LDS-reduce, 2 global atomicAdds/row
// (exactly 2 contributions per address -> deterministic).
// ALPHA_MODE 2: block covers ALL cols (NTOT<=64): direct store, no atomics.

template <int WAVES_M, int WAVES_N, int KTOT, bool A_FP32, int ALPHA_MODE>
__global__ __launch_bounds__(256) void mfma_gemm(
    const void* __restrict__ Aptr, const ushort_t* __restrict__ Bt,
    ushort_t* __restrict__ Out, int M, int NTOT,
    const float* __restrict__ av_s, const float* __restrict__ av_d,
    float* __restrict__ os, float* __restrict__ od) {
  constexpr int BM = 128;
  constexpr int WN = 64;
  constexpr int WM = BM / WAVES_M;
  constexpr int M_REP = WM / 16;
  constexpr int N_REP = WN / 16;
  constexpr int KC = 128;
  __shared__ ushort_t As[BM * KC];
  __shared__ float als_s[BM], als_d[BM];

  const int tid = threadIdx.x;
  const int lane = tid & 63;
  const int wid = tid >> 6;
  const int wm = wid % WAVES_M;
  const int wn = wid / WAVES_M;
  const int rowBase = blockIdx.x * BM;
  const int colBase = blockIdx.y * (WAVES_N * WN) + wn * WN;
  const int l15 = lane & 15;
  const int l4 = lane >> 4;

  if (ALPHA_MODE == 1) {
    for (int rr = tid; rr < BM; rr += 256) { als_s[rr] = 0.f; als_d[rr] = 0.f; }
  }

  f32x4 acc[M_REP][N_REP] = {};

  for (int kc = 0; kc < KTOT; kc += KC) {
    if (kc) __syncthreads();
    for (int c = tid; c < BM * KC / 8; c += 256) {
      int r = c >> 4;
      int k8 = (c & 15) << 3;
      int gr = rowBase + r;
      short8v u = {};
      if (gr < M) {
        if (A_FP32) {
          const float* A = (const float*)Aptr;
          float4 f0 = *(const float4*)&A[(size_t)gr * KTOT + kc + k8];
          float4 f1 = *(const float4*)&A[(size_t)gr * KTOT + kc + k8 + 4];
          u[0] = (short)f2b(f0.x); u[1] = (short)f2b(f0.y);
          u[2] = (short)f2b(f0.z); u[3] = (short)f2b(f0.w);
          u[4] = (short)f2b(f1.x); u[5] = (short)f2b(f1.y);
          u[6] = (short)f2b(f1.z); u[7] = (short)f2b(f1.w);
        } else {
          const ushort_t* A = (const ushort_t*)Aptr;
          u = *(const short8v*)&A[(size_t)gr * KTOT + kc + k8];
        }
      }
      int byte = (r * KC + k8) * 2;
      byte ^= (r & 7) << 4;  // G4 swizzle
      *(short8v*)((char*)As + byte) = u;
    }
    short8v bfr[KC / 32][N_REP];
#pragma unroll
    for (int kk = 0; kk < KC / 32; ++kk)
#pragma unroll
      for (int n = 0; n < N_REP; ++n) {
        int bcol = colBase + n * 16 + l15;
        int k0 = kc + kk * 32 + l4 * 8;
        bfr[kk][n] = *(const short8v*)&Bt[(size_t)bcol * KTOT + k0];
      }
    __syncthreads();
#pragma unroll
    for (int kk = 0; kk < KC / 32; ++kk) {
      short8v afr[M_REP];
#pragma unroll
      for (int m = 0; m < M_REP; ++m) {
        int r = wm * WM + m * 16 + l15;
        int k0 = kk * 32 + l4 * 8;
        int byte = ((r * KC + k0) * 2) ^ ((r & 7) << 4);
        afr[m] = *(const short8v*)((const char*)As + byte);
      }
#pragma unroll
      for (int m = 0; m < M_REP; ++m)
#pragma unroll
        for (int n = 0; n < N_REP; ++n)
          acc[m][n] = __builtin_amdgcn_mfma_f32_16x16x32_bf16(
              afr[m], bfr[kk][n], acc[m][n], 0, 0, 0);
    }
  }
  // C write: col=lane&15, row=(lane>>4)*4+reg
#pragma unroll
  for (int m = 0; m < M_REP; ++m) {
    int r0 = rowBase + wm * WM + m * 16 + l4 * 4;
#pragma unroll
    for (int n = 0; n < N_REP; ++n) {
      int gc = colBase + n * 16 + l15;
#pragma unroll
      for (int j = 0; j < 4; ++j) {
        int gr = r0 + j;
        if (gr < M) Out[(size_t)gr * NTOT + gc] = f2b(acc[m][n][j]);
      }
    }
  }
  // fused alpha epilogue
  if (ALPHA_MODE) {
    float as_v[N_REP], ad_v[N_REP];
#pragma unroll
    for (int n = 0; n < N_REP; ++n) {
      as_v[n] = av_s[colBase + n * 16 + l15];
      ad_v[n] = av_d[colBase + n * 16 + l15];
    }
#pragma unroll
    for (int m = 0; m < M_REP; ++m)
#pragma unroll
      for (int j = 0; j < 4; ++j) {
        float ss = 0.f, dd = 0.f;
#pragma unroll
        for (int n = 0; n < N_REP; ++n) {
          ss += acc[m][n][j] * as_v[n];
          dd += acc[m][n][j] * ad_v[n];
        }
#pragma unroll
        for (int o = 1; o < 16; o <<= 1) {
          ss += __shfl_xor(ss, o);
          dd += __shfl_xor(dd, o);
        }
        if (l15 == 0) {
          int rloc = wm * WM + m * 16 + l4 * 4 + j;
          if (ALPHA_MODE == 1) {
            atomicAdd(&als_s[rloc], ss);
            atomicAdd(&als_d[rloc], dd);
          } else {
            int gr = rowBase + rloc;
            if (gr < M) { os[gr] = ss; od[gr] = dd; }
          }
        }
      }
    if (ALPHA_MODE == 1) {
      __syncthreads();
      for (int rr = tid; rr < BM; rr += 256) {
        int gr = rowBase + rr;
        if (gr < M) {
          atomicAdd(&os[gr], als_s[rr]);
          atomicAdd(&od[gr], als_d[rr]);
        }
      }
    }
  }
}

// ---------------- fused softmax + aggregation ----------------

// layer 1: lane = 4 channels (C=256, 512B rows); fused relu(acc+b1) -> bf16
__global__ __launch_bounds__(256) void fused_agg1(
    const ushort_t* __restrict__ h, const int* __restrict__ rowptr,
    const int* __restrict__ col, const float* __restrict__ asrc,
    const float* __restrict__ adst, const float* __restrict__ bias,
    ushort_t* __restrict__ out) {
  __shared__ float wlds[4][64];
  __shared__ int clds[4][64];
  int wid = threadIdx.x >> 6;
  int n = blockIdx.x * 4 + wid;
  if (n >= N_NODES) return;
  int lane = threadIdx.x & 63;
  int beg = rowptr[n], end = rowptr[n + 1];
  int deg = end - beg;
  float ad = adst[n];
  float we = 0.f;
  int s = 0;
  if (lane < deg) { s = col[beg + lane]; we = __expf(leaky(asrc[s] + ad)); }
  float ssum = we;
  for (int jj = beg + 64 + lane; jj < end; jj += 64)   // essentially never
    ssum += __expf(leaky(asrc[col[jj]] + ad));
#pragma unroll
  for (int off = 32; off; off >>= 1) ssum += __shfl_xor(ssum, off);
  float inv = 1.0f / ssum;
  wlds[wid][lane] = we * inv;
  clds[wid][lane] = s << 9;   // byte offset of 512B row
  float a0 = 0.f, a1 = 0.f, a2 = 0.f, a3 = 0.f;
  const char* hb = (const char*)h + lane * 8;
  if (deg <= 64) {
    int t = 0;
    for (; t + 8 <= deg; t += 8) {
      int4 cA = *reinterpret_cast<const int4*>(&clds[wid][t]);
      int4 cB = *reinterpret_cast<const int4*>(&clds[wid][t + 4]);
      float4 wA = *reinterpret_cast<const float4*>(&wlds[wid][t]);
      float4 wB = *reinterpret_cast<const float4*>(&wlds[wid][t + 4]);
      ushort4 u0 = *reinterpret_cast<const ushort4*>(hb + cA.x);
      ushort4 u1 = *reinterpret_cast<const ushort4*>(hb + cA.y);
      ushort4 u2 = *reinterpret_cast<const ushort4*>(hb + cA.z);
      ushort4 u3 = *reinterpret_cast<const ushort4*>(hb + cA.w);
      ushort4 u4 = *reinterpret_cast<const ushort4*>(hb + cB.x);
      ushort4 u5 = *reinterpret_cast<const ushort4*>(hb + cB.y);
      ushort4 u6 = *reinterpret_cast<const ushort4*>(hb + cB.z);
      ushort4 u7 = *reinterpret_cast<const ushort4*>(hb + cB.w);
      a0 += wA.x * b2f(u0.x) + wA.y * b2f(u1.x) + wA.z * b2f(u2.x) + wA.w * b2f(u3.x)
          + wB.x * b2f(u4.x) + wB.y * b2f(u5.x) + wB.z * b2f(u6.x) + wB.w * b2f(u7.x);
      a1 += wA.x * b2f(u0.y) + wA.y * b2f(u1.y) + wA.z * b2f(u2.y) + wA.w * b2f(u3.y)
          + wB.x * b2f(u4.y) + wB.y * b2f(u5.y) + wB.z * b2f(u6.y) + wB.w * b2f(u7.y);
      a2 += wA.x * b2f(u0.z) + wA.y * b2f(u1.z) + wA.z * b2f(u2.z) + wA.w * b2f(u3.z)
          + wB.x * b2f(u4.z) + wB.y * b2f(u5.z) + wB.z * b2f(u6.z) + wB.w * b2f(u7.z);
      a3 += wA.x * b2f(u0.w) + wA.y * b2f(u1.w) + wA.z * b2f(u2.w) + wA.w * b2f(u3.w)
          + wB.x * b2f(u4.w) + wB.y * b2f(u5.w) + wB.z * b2f(u6.w) + wB.w * b2f(u7.w);
    }
    for (; t < deg; ++t) {
      int c = clds[wid][t];
      float w = wlds[wid][t];
      ushort4 u = *reinterpret_cast<const ushort4*>(hb + c);
      a0 += w * b2f(u.x); a1 += w * b2f(u.y);
      a2 += w * b2f(u.z); a3 += w * b2f(u.w);
    }
  } else {  // deg > 64: recompute weights (astronomically rare)
    for (int j = beg; j < end; ++j) {
      int sj = col[j];
      float w = __expf(leaky(asrc[sj] + ad)) * inv;
      ushort4 u = *reinterpret_cast<const ushort4*>(&h[(size_t)sj * 256 + lane * 4]);
      a0 += w * b2f(u.x); a1 += w * b2f(u.y);
      a2 += w * b2f(u.z); a3 += w * b2f(u.w);
    }
  }
  float4 bv = *reinterpret_cast<const float4*>(&bias[lane * 4]);
  ushort4 o;
  o.x = f2b(fmaxf(a0 + bv.x, 0.f));
  o.y = f2b(fmaxf(a1 + bv.y, 0.f));
  o.z = f2b(fmaxf(a2 + bv.z, 0.f));
  o.w = f2b(fmaxf(a3 + bv.w, 0.f));
  *reinterpret_cast<ushort4*>(&out[(size_t)n * 256 + lane * 4]) = o;
}

// layer 2: lane = 1 channel (C=64, 128B rows); fused +bias, final fp32 out
__global__ __launch_bounds__(256) void fused_agg2(
    const ushort_t* __restrict__ h, const int* __restrict__ rowptr,
    const int* __restrict__ col, const float* __restrict__ asrc,
    const float* __restrict__ adst, const float* __restrict__ bias,
    float* __restrict__ out) {
  __shared__ float wlds[4][64];
  __shared__ int clds[4][64];
  int wid = threadIdx.x >> 6;
  int n = blockIdx.x * 4 + wid;
  if (n >= N_NODES) return;
  int lane = threadIdx.x & 63;
  int beg = rowptr[n], end = rowptr[n + 1];
  int deg = end - beg;
  float ad = adst[n];
  float we = 0.f;
  int s = 0;
  if (lane < deg) { s = col[beg + lane]; we = __expf(leaky(asrc[s] + ad)); }
  float ssum = we;
  for (int jj = beg + 64 + lane; jj < end; jj += 64)
    ssum += __expf(leaky(asrc[col[jj]] + ad));
#pragma unroll
  for (int off = 32; off; off >>= 1) ssum += __shfl_xor(ssum, off);
  float inv = 1.0f / ssum;
  wlds[wid][lane] = we * inv;
  clds[wid][lane] = s << 7;   // byte offset of 128B row
  float acc = 0.f;
  const char* hb = (const char*)h + lane * 2;
  if (deg <= 64) {
    int t = 0;
    for (; t + 8 <= deg; t += 8) {
      int4 cA = *reinterpret_cast<const int4*>(&clds[wid][t]);
      int4 cB = *reinterpret_cast<const int4*>(&clds[wid][t + 4]);
      float4 wA = *reinterpret_cast<const float4*>(&wlds[wid][t]);
      float4 wB = *reinterpret_cast<const float4*>(&wlds[wid][t + 4]);
      ushort_t u0 = *reinterpret_cast<const ushort_t*>(hb + cA.x);
      ushort_t u1 = *reinterpret_cast<const ushort_t*>(hb + cA.y);
      ushort_t u2 = *reinterpret_cast<const ushort_t*>(hb + cA.z);
      ushort_t u3 = *reinterpret_cast<const ushort_t*>(hb + cA.w);
      ushort_t u4 = *reinterpret_cast<const ushort_t*>(hb + cB.x);
      ushort_t u5 = *reinterpret_cast<const ushort_t*>(hb + cB.y);
      ushort_t u6 = *reinterpret_cast<const ushort_t*>(hb + cB.z);
      ushort_t u7 = *reinterpret_cast<const ushort_t*>(hb + cB.w);
      acc += wA.x * b2f(u0) + wA.y * b2f(u1) + wA.z * b2f(u2) + wA.w * b2f(u3)
           + wB.x * b2f(u4) + wB.y * b2f(u5) + wB.z * b2f(u6) + wB.w * b2f(u7);
    }
    for (; t < deg; ++t)
      acc += wlds[wid][t] * b2f(*reinterpret_cast<const ushort_t*>(hb + clds[wid][t]));
  } else {
    for (int j = beg; j < end; ++j) {
      int sj = col[j];
      float w = __expf(leaky(asrc[sj] + ad)) * inv;
      acc += w * b2f(h[(size_t)sj * 64 + lane]);
    }
  }
  out[(size_t)n * 64 + lane] = acc + bias[lane];
}

// ---------------- launch ----------------

extern "C" void kernel_launch(void* const* d_in, const int* in_sizes, int n_in,
                              void* d_out, int out_size, void* d_ws, size_t ws_size,
                              hipStream_t stream) {
  const float* x    = (const float*)d_in[0];
  const int*   ei   = (const int*)d_in[1];
  const float* W1   = (const float*)d_in[2];
  const float* a1s  = (const float*)d_in[3];
  const float* a1d  = (const float*)d_in[4];
  const float* b1   = (const float*)d_in[5];
  const float* W2   = (const float*)d_in[6];
  const float* a2s  = (const float*)d_in[7];
  const float* a2d  = (const float*)d_in[8];
  const float* b2   = (const float*)d_in[9];
  float* out = (float*)d_out;

  char* ws = (char*)d_ws;
  size_t off = 0;
  auto alloc = [&](size_t bytes) {
    void* p = ws + off;
    off += bytes;
    off = (off + 255) & ~(size_t)255;
    return p;
  };

  ushort_t* h1   = (ushort_t*)alloc((size_t)N_NODES * 256 * 2);  // bf16
  ushort_t* a1b  = (ushort_t*)alloc((size_t)N_NODES * 256 * 2);  // bf16 relu(agg1+b1)
  ushort_t* h2   = (ushort_t*)alloc((size_t)N_NODES * 64 * 2);   // bf16
  ushort_t* W1t  = (ushort_t*)alloc((size_t)256 * 128 * 2);
  ushort_t* W2t  = (ushort_t*)alloc((size_t)64 * 256 * 2);
  float* asrc1   = (float*)alloc((size_t)N_NODES * 4);
  float* adst1   = (float*)alloc((size_t)N_NODES * 4);
  int*   deg     = (int*)alloc((size_t)N_NODES * 4);
  float* asrc2   = (float*)alloc((size_t)N_NODES * 4);
  float* adst2   = (float*)alloc((size_t)N_NODES * 4);
  int*   rowptr  = (int*)alloc((size_t)(N_NODES + 1) * 4);
  int*   fillp   = (int*)alloc((size_t)N_NODES * 4);
  int*   col     = (int*)alloc((size_t)E_TOT * 4);
  int*   bsums   = (int*)alloc((size_t)256 * 4);

  const int nodeBlocks4 = (N_NODES + 3) / 4;
  const int gemmBlocksM = (N_NODES + 127) / 128;

  // CSR build + prep: one cooperative kernel
  {
    void* args[] = {
      (void*)&ei, (void*)&deg, (void*)&W1, (void*)&W1t, (void*)&W2, (void*)&W2t,
      (void*)&rowptr, (void*)&fillp, (void*)&col, (void*)&bsums,
      (void*)&asrc1, (void*)&adst1
    };
    hipLaunchCooperativeKernel((void*)csr_coop, dim3(256), dim3(256), args, 0, stream);
  }

  // layer 1: h1 = bf16(x) @ W1t^T, alpha partials via atomics
  mfma_gemm<2, 2, 128, true, 1><<<dim3(gemmBlocksM, 2), 256, 0, stream>>>(
      x, W1t, h1, N_NODES, 256, a1s, a1d, asrc1, adst1);
  fused_agg1<<<nodeBlocks4, 256, 0, stream>>>(h1, rowptr, col, asrc1, adst1, b1, a1b);

  // layer 2: h2 = a1b @ W2t^T, alpha direct
  mfma_gemm<4, 1, 256, false, 2><<<dim3(gemmBlocksM, 1), 256, 0, stream>>>(
      a1b, W2t, h2, N_NODES, 64, a2s, a2d, asrc2, adst2);
  fused_agg2<<<nodeBlocks4, 256, 0, stream>>>(h2, rowptr, col, asrc2, adst2, b2, out);
}

// Round 10
// 304.084 us; speedup vs baseline: 1.4253x; 1.4253x over previous
//
#include <hip/hip_runtime.h>
#include <math.h>

#define N_NODES 100000
#define N_EDGES 800000
#define E_TOT (N_EDGES + N_NODES)
#define NEG_SLOPE 0.2f
#define SCAN_NB ((N_NODES + 1023) / 1024)
#define EB ((E_TOT + 255) / 256)
#define GBM ((N_NODES + 127) / 128)

typedef unsigned short ushort_t;
typedef unsigned long long ull_t;
typedef __attribute__((ext_vector_type(8))) short short8v;   // 8 bf16
typedef __attribute__((ext_vector_type(4))) float f32x4;

static __device__ __forceinline__ float leaky(float e) {
  return e > 0.f ? e : NEG_SLOPE * e;
}

static __device__ __forceinline__ float b2f(ushort_t u) {
  union { unsigned int i; float f; } x;
  x.i = ((unsigned int)u) << 16;
  return x.f;
}

static __device__ __forceinline__ ushort_t f2b(float f) {
  union { float f; unsigned int i; } x;
  x.f = f;
  unsigned int r = x.i + 0x7FFFu + ((x.i >> 16) & 1u);  // RNE (finite inputs)
  return (ushort_t)(r >> 16);
}

// ---------------- prep: zero buffers + weight transposes (absorbs memset) ----------------

__global__ void prep_kernel(int* __restrict__ deg, float* __restrict__ asrc1,
                            float* __restrict__ adst1, ull_t* __restrict__ state,
                            const float* __restrict__ W1, ushort_t* __restrict__ W1t,
                            const float* __restrict__ W2, ushort_t* __restrict__ W2t) {
  int g = blockIdx.x * 256 + threadIdx.x;
  const int GT = gridDim.x * 256;
  for (int i = g; i < N_NODES; i += GT) { deg[i] = 0; asrc1[i] = 0.f; adst1[i] = 0.f; }
  for (int i = g; i < 256 * 128; i += GT) {       // W1t[n][k] = W1[k][n]
    int n = i >> 7, k = i & 127;
    W1t[i] = f2b(W1[(size_t)k * 256 + n]);
  }
  for (int i = g; i < 64 * 256; i += GT) {        // W2t[n][k] = W2[k][n]
    int n = i >> 8, k = i & 255;
    W2t[i] = f2b(W2[(size_t)k * 64 + n]);
  }
  for (int i = g; i < SCAN_NB; i += GT) state[i] = 0;
}

// ---------------- GEMM body (device fn; callable from merged dispatch) ----------------
// ALPHA_MODE 1: per-row partial alpha dots; LDS-reduce, 2 global atomicAdds/row
// (exactly 2 contributions per address -> deterministic).
// ALPHA_MODE 2: block covers ALL cols: direct store, no atomics.

template <int WAVES_M, int WAVES_N, int KTOT, bool A_FP32, int ALPHA_MODE>
static __device__ void gemm_body(
    int bx, int by,
    const void* __restrict__ Aptr, const ushort_t* __restrict__ Bt,
    ushort_t* __restrict__ Out, int M, int NTOT,
    const float* __restrict__ av_s, const float* __restrict__ av_d,
    float* __restrict__ os, float* __restrict__ od) {
  constexpr int BM = 128;
  constexpr int WN = 64;
  constexpr int WM = BM / WAVES_M;
  constexpr int M_REP = WM / 16;
  constexpr int N_REP = WN / 16;
  constexpr int KC = 128;
  __shared__ ushort_t As[BM * KC];
  __shared__ float als_s[BM], als_d[BM];

  const int tid = threadIdx.x;
  const int lane = tid & 63;
  const int wid = tid >> 6;
  const int wm = wid % WAVES_M;
  const int wn = wid / WAVES_M;
  const int rowBase = bx * BM;
  const int colBase = by * (WAVES_N * WN) + wn * WN;
  const int l15 = lane & 15;
  const int l4 = lane >> 4;

  if (ALPHA_MODE == 1) {
    for (int rr = tid; rr < BM; rr += 256) { als_s[rr] = 0.f; als_d[rr] = 0.f; }
  }

  f32x4 acc[M_REP][N_REP] = {};

  for (int kc = 0; kc < KTOT; kc += KC) {
    if (kc) __syncthreads();
    for (int c = tid; c < BM * KC / 8; c += 256) {
      int r = c >> 4;
      int k8 = (c & 15) << 3;
      int gr = rowBase + r;
      short8v u = {};
      if (gr < M) {
        if (A_FP32) {
          const float* A = (const float*)Aptr;
          float4 f0 = *(const float4*)&A[(size_t)gr * KTOT + kc + k8];
          float4 f1 = *(const float4*)&A[(size_t)gr * KTOT + kc + k8 + 4];
          u[0] = (short)f2b(f0.x); u[1] = (short)f2b(f0.y);
          u[2] = (short)f2b(f0.z); u[3] = (short)f2b(f0.w);
          u[4] = (short)f2b(f1.x); u[5] = (short)f2b(f1.y);
          u[6] = (short)f2b(f1.z); u[7] = (short)f2b(f1.w);
        } else {
          const ushort_t* A = (const ushort_t*)Aptr;
          u = *(const short8v*)&A[(size_t)gr * KTOT + kc + k8];
        }
      }
      int byte = (r * KC + k8) * 2;
      byte ^= (r & 7) << 4;  // G4 swizzle
      *(short8v*)((char*)As + byte) = u;
    }
    short8v bfr[KC / 32][N_REP];
#pragma unroll
    for (int kk = 0; kk < KC / 32; ++kk)
#pragma unroll
      for (int n = 0; n < N_REP; ++n) {
        int bcol = colBase + n * 16 + l15;
        int k0 = kc + kk * 32 + l4 * 8;
        bfr[kk][n] = *(const short8v*)&Bt[(size_t)bcol * KTOT + k0];
      }
    __syncthreads();
#pragma unroll
    for (int kk = 0; kk < KC / 32; ++kk) {
      short8v afr[M_REP];
#pragma unroll
      for (int m = 0; m < M_REP; ++m) {
        int r = wm * WM + m * 16 + l15;
        int k0 = kk * 32 + l4 * 8;
        int byte = ((r * KC + k0) * 2) ^ ((r & 7) << 4);
        afr[m] = *(const short8v*)((const char*)As + byte);
      }
#pragma unroll
      for (int m = 0; m < M_REP; ++m)
#pragma unroll
        for (int n = 0; n < N_REP; ++n)
          acc[m][n] = __builtin_amdgcn_mfma_f32_16x16x32_bf16(
              afr[m], bfr[kk][n], acc[m][n], 0, 0, 0);
    }
  }
  // C write: col=lane&15, row=(lane>>4)*4+reg
#pragma unroll
  for (int m = 0; m < M_REP; ++m) {
    int r0 = rowBase + wm * WM + m * 16 + l4 * 4;
#pragma unroll
    for (int n = 0; n < N_REP; ++n) {
      int gc = colBase + n * 16 + l15;
#pragma unroll
      for (int j = 0; j < 4; ++j) {
        int gr = r0 + j;
        if (gr < M) Out[(size_t)gr * NTOT + gc] = f2b(acc[m][n][j]);
      }
    }
  }
  // fused alpha epilogue
  if (ALPHA_MODE) {
    float as_v[N_REP], ad_v[N_REP];
#pragma unroll
    for (int n = 0; n < N_REP; ++n) {
      as_v[n] = av_s[colBase + n * 16 + l15];
      ad_v[n] = av_d[colBase + n * 16 + l15];
    }
#pragma unroll
    for (int m = 0; m < M_REP; ++m)
#pragma unroll
      for (int j = 0; j < 4; ++j) {
        float ss = 0.f, dd = 0.f;
#pragma unroll
        for (int n = 0; n < N_REP; ++n) {
          ss += acc[m][n][j] * as_v[n];
          dd += acc[m][n][j] * ad_v[n];
        }
#pragma unroll
        for (int o = 1; o < 16; o <<= 1) {
          ss += __shfl_xor(ss, o);
          dd += __shfl_xor(dd, o);
        }
        if (l15 == 0) {
          int rloc = wm * WM + m * 16 + l4 * 4 + j;
          if (ALPHA_MODE == 1) {
            atomicAdd(&als_s[rloc], ss);
            atomicAdd(&als_d[rloc], dd);
          } else {
            int gr = rowBase + rloc;
            if (gr < M) { os[gr] = ss; od[gr] = dd; }
          }
        }
      }
    if (ALPHA_MODE == 1) {
      __syncthreads();
      for (int rr = tid; rr < BM; rr += 256) {
        int gr = rowBase + rr;
        if (gr < M) {
          atomicAdd(&os[gr], als_s[rr]);
          atomicAdd(&od[gr], als_d[rr]);
        }
      }
    }
  }
}

// ---------------- merged dispatch: GEMM1 blocks + degree-histogram blocks ----------------

__global__ __launch_bounds__(256) void hist_gemm1(
    const float* __restrict__ x, const ushort_t* __restrict__ W1t,
    ushort_t* __restrict__ h1,
    const float* __restrict__ a1s, const float* __restrict__ a1d,
    float* __restrict__ asrc1, float* __restrict__ adst1,
    const int* __restrict__ ei, int* __restrict__ deg) {
  int gb = blockIdx.x;
  if (gb < GBM * 2) {
    gemm_body<2, 2, 128, true, 1>(gb % GBM, gb / GBM, x, W1t, h1, N_NODES, 256,
                                  a1s, a1d, asrc1, adst1);
  } else {
    int e = (gb - GBM * 2) * 256 + threadIdx.x;
    if (e < E_TOT) {
      int d = (e < N_EDGES) ? ei[N_EDGES + e] : (e - N_EDGES);
      atomicAdd(&deg[d], 1);
    }
  }
}

__global__ __launch_bounds__(256) void gemm2_kernel(
    const ushort_t* __restrict__ a1b, const ushort_t* __restrict__ W2t,
    ushort_t* __restrict__ h2,
    const float* __restrict__ a2s, const float* __restrict__ a2d,
    float* __restrict__ asrc2, float* __restrict__ adst2) {
  gemm_body<4, 1, 256, false, 2>(blockIdx.x, 0, a1b, W2t, h2, N_NODES, 64,
                                 a2s, a2d, asrc2, adst2);
}

// ---------------- single-pass decoupled-lookback scan ----------------
// state[b]: packed (flag<<32)|value; flag 1=block aggregate, 2=inclusive prefix.
// All SCAN_NB=98 blocks co-resident (98 < 256 CUs) -> spin is safe.

__global__ __launch_bounds__(1024) void scan_lookback(
    const int* __restrict__ deg, ull_t* __restrict__ state,
    int* __restrict__ rowptr, int* __restrict__ fillpos) {
  __shared__ int sh[1024];
  __shared__ int boff_sh;
  const int tid = threadIdx.x;
  const int bid = blockIdx.x;
  int i = bid * 1024 + tid;
  int v = (i < N_NODES) ? deg[i] : 0;
  sh[tid] = v;
  __syncthreads();
  for (int off = 1; off < 1024; off <<= 1) {
    int t = (tid >= off) ? sh[tid - off] : 0;
    __syncthreads();
    sh[tid] += t;
    __syncthreads();
  }
  if (tid == 0) {
    int total = sh[1023];
    atomicExch(&state[bid], (1ULL << 32) | (unsigned int)total);
    long long excl = 0;
    int p = bid - 1;
    while (p >= 0) {
      ull_t st;
      do { st = atomicAdd(&state[p], 0ULL); } while (st == 0);
      excl += (int)(st & 0xffffffffULL);
      if ((st >> 32) == 2) break;
      --p;
    }
    atomicExch(&state[bid], (2ULL << 32) | (unsigned int)(excl + total));
    boff_sh = (int)excl;
  }
  __syncthreads();
  if (i < N_NODES) {
    int excl = sh[tid] - v + boff_sh;
    rowptr[i] = excl;
    fillpos[i] = excl;
    if (i == N_NODES - 1) rowptr[N_NODES] = excl + v;
  }
}

__global__ void fill_kernel(const int* __restrict__ ei, int* __restrict__ fillpos,
                            int* __restrict__ col) {
  int e = blockIdx.x * 256 + threadIdx.x;
  if (e >= E_TOT) return;
  int s, d;
  if (e < N_EDGES) { s = ei[e]; d = ei[N_EDGES + e]; }
  else { s = d = e - N_EDGES; }
  int p = atomicAdd(&fillpos[d], 1);
  col[p] = s;
}

// ---------------- fused softmax + aggregation ----------------

// layer 1: lane = 4 channels (C=256, 512B rows); fused relu(acc+b1) -> bf16
__global__ __launch_bounds__(256) void fused_agg1(
    const ushort_t* __restrict__ h, const int* __restrict__ rowptr,
    const int* __restrict__ col, const float* __restrict__ asrc,
    const float* __restrict__ adst, const float* __restrict__ bias,
    ushort_t* __restrict__ out) {
  __shared__ float wlds[4][64];
  __shared__ int clds[4][64];
  int wid = threadIdx.x >> 6;
  int n = blockIdx.x * 4 + wid;
  if (n >= N_NODES) return;
  int lane = threadIdx.x & 63;
  int beg = rowptr[n], end = rowptr[n + 1];
  int deg = end - beg;
  float ad = adst[n];
  float we = 0.f;
  int s = 0;
  if (lane < deg) { s = col[beg + lane]; we = __expf(leaky(asrc[s] + ad)); }
  float ssum = we;
  for (int jj = beg + 64 + lane; jj < end; jj += 64)   // essentially never
    ssum += __expf(leaky(asrc[col[jj]] + ad));
#pragma unroll
  for (int off = 32; off; off >>= 1) ssum += __shfl_xor(ssum, off);
  float inv = 1.0f / ssum;
  wlds[wid][lane] = we * inv;
  clds[wid][lane] = s << 9;   // byte offset of 512B row
  float a0 = 0.f, a1 = 0.f, a2 = 0.f, a3 = 0.f;
  const char* hb = (const char*)h + lane * 8;
  if (deg <= 64) {
    int t = 0;
    for (; t + 8 <= deg; t += 8) {
      int4 cA = *reinterpret_cast<const int4*>(&clds[wid][t]);
      int4 cB = *reinterpret_cast<const int4*>(&clds[wid][t + 4]);
      float4 wA = *reinterpret_cast<const float4*>(&wlds[wid][t]);
      float4 wB = *reinterpret_cast<const float4*>(&wlds[wid][t + 4]);
      ushort4 u0 = *reinterpret_cast<const ushort4*>(hb + cA.x);
      ushort4 u1 = *reinterpret_cast<const ushort4*>(hb + cA.y);
      ushort4 u2 = *reinterpret_cast<const ushort4*>(hb + cA.z);
      ushort4 u3 = *reinterpret_cast<const ushort4*>(hb + cA.w);
      ushort4 u4 = *reinterpret_cast<const ushort4*>(hb + cB.x);
      ushort4 u5 = *reinterpret_cast<const ushort4*>(hb + cB.y);
      ushort4 u6 = *reinterpret_cast<const ushort4*>(hb + cB.z);
      ushort4 u7 = *reinterpret_cast<const ushort4*>(hb + cB.w);
      a0 += wA.x * b2f(u0.x) + wA.y * b2f(u1.x) + wA.z * b2f(u2.x) + wA.w * b2f(u3.x)
          + wB.x * b2f(u4.x) + wB.y * b2f(u5.x) + wB.z * b2f(u6.x) + wB.w * b2f(u7.x);
      a1 += wA.x * b2f(u0.y) + wA.y * b2f(u1.y) + wA.z * b2f(u2.y) + wA.w * b2f(u3.y)
          + wB.x * b2f(u4.y) + wB.y * b2f(u5.y) + wB.z * b2f(u6.y) + wB.w * b2f(u7.y);
      a2 += wA.x * b2f(u0.z) + wA.y * b2f(u1.z) + wA.z * b2f(u2.z) + wA.w * b2f(u3.z)
          + wB.x * b2f(u4.z) + wB.y * b2f(u5.z) + wB.z * b2f(u6.z) + wB.w * b2f(u7.z);
      a3 += wA.x * b2f(u0.w) + wA.y * b2f(u1.w) + wA.z * b2f(u2.w) + wA.w * b2f(u3.w)
          + wB.x * b2f(u4.w) + wB.y * b2f(u5.w) + wB.z * b2f(u6.w) + wB.w * b2f(u7.w);
    }
    for (; t < deg; ++t) {
      int c = clds[wid][t];
      float w = wlds[wid][t];
      ushort4 u = *reinterpret_cast<const ushort4*>(hb + c);
      a0 += w * b2f(u.x); a1 += w * b2f(u.y);
      a2 += w * b2f(u.z); a3 += w * b2f(u.w);
    }
  } else {  // deg > 64: recompute weights (astronomically rare)
    for (int j = beg; j < end; ++j) {
      int sj = col[j];
      float w = __expf(leaky(asrc[sj] + ad)) * inv;
      ushort4 u = *reinterpret_cast<const ushort4*>(&h[(size_t)sj * 256 + lane * 4]);
      a0 += w * b2f(u.x); a1 += w * b2f(u.y);
      a2 += w * b2f(u.z); a3 += w * b2f(u.w);
    }
  }
  float4 bv = *reinterpret_cast<const float4*>(&bias[lane * 4]);
  ushort4 o;
  o.x = f2b(fmaxf(a0 + bv.x, 0.f));
  o.y = f2b(fmaxf(a1 + bv.y, 0.f));
  o.z = f2b(fmaxf(a2 + bv.z, 0.f));
  o.w = f2b(fmaxf(a3 + bv.w, 0.f));
  *reinterpret_cast<ushort4*>(&out[(size_t)n * 256 + lane * 4]) = o;
}

// layer 2: lane = 1 channel (C=64, 128B rows); fused +bias, final fp32 out
__global__ __launch_bounds__(256) void fused_agg2(
    const ushort_t* __restrict__ h, const int* __restrict__ rowptr,
    const int* __restrict__ col, const float* __restrict__ asrc,
    const float* __restrict__ adst, const float* __restrict__ bias,
    float* __restrict__ out) {
  __shared__ float wlds[4][64];
  __shared__ int clds[4][64];
  int wid = threadIdx.x >> 6;
  int n = blockIdx.x * 4 + wid;
  if (n >= N_NODES) return;
  int lane = threadIdx.x & 63;
  int beg = rowptr[n], end = rowptr[n + 1];
  int deg = end - beg;
  float ad = adst[n];
  float we = 0.f;
  int s = 0;
  if (lane < deg) { s = col[beg + lane]; we = __expf(leaky(asrc[s] + ad)); }
  float ssum = we;
  for (int jj = beg + 64 + lane; jj < end; jj += 64)
    ssum += __expf(leaky(asrc[col[jj]] + ad));
#pragma unroll
  for (int off = 32; off; off >>= 1) ssum += __shfl_xor(ssum, off);
  float inv = 1.0f / ssum;
  wlds[wid][lane] = we * inv;
  clds[wid][lane] = s << 7;   // byte offset of 128B row
  float acc = 0.f;
  const char* hb = (const char*)h + lane * 2;
  if (deg <= 64) {
    int t = 0;
    for (; t + 8 <= deg; t += 8) {
      int4 cA = *reinterpret_cast<const int4*>(&clds[wid][t]);
      int4 cB = *reinterpret_cast<const int4*>(&clds[wid][t + 4]);
      float4 wA = *reinterpret_cast<const float4*>(&wlds[wid][t]);
      float4 wB = *reinterpret_cast<const float4*>(&wlds[wid][t + 4]);
      ushort_t u0 = *reinterpret_cast<const ushort_t*>(hb + cA.x);
      ushort_t u1 = *reinterpret_cast<const ushort_t*>(hb + cA.y);
      ushort_t u2 = *reinterpret_cast<const ushort_t*>(hb + cA.z);
      ushort_t u3 = *reinterpret_cast<const ushort_t*>(hb + cA.w);
      ushort_t u4 = *reinterpret_cast<const ushort_t*>(hb + cB.x);
      ushort_t u5 = *reinterpret_cast<const ushort_t*>(hb + cB.y);
      ushort_t u6 = *reinterpret_cast<const ushort_t*>(hb + cB.z);
      ushort_t u7 = *reinterpret_cast<const ushort_t*>(hb + cB.w);
      acc += wA.x * b2f(u0) + wA.y * b2f(u1) + wA.z * b2f(u2) + wA.w * b2f(u3)
           + wB.x * b2f(u4) + wB.y * b2f(u5) + wB.z * b2f(u6) + wB.w * b2f(u7);
    }
    for (; t < deg; ++t)
      acc += wlds[wid][t] * b2f(*reinterpret_cast<const ushort_t*>(hb + clds[wid][t]));
  } else {
    for (int j = beg; j < end; ++j) {
      int sj = col[j];
      float w = __expf(leaky(asrc[sj] + ad)) * inv;
      acc += w * b2f(h[(size_t)sj * 64 + lane]);
    }
  }
  out[(size_t)n * 64 + lane] = acc + bias[lane];
}

// ---------------- launch ----------------

extern "C" void kernel_launch(void* const* d_in, const int* in_sizes, int n_in,
                              void* d_out, int out_size, void* d_ws, size_t ws_size,
                              hipStream_t stream) {
  const float* x    = (const float*)d_in[0];
  const int*   ei   = (const int*)d_in[1];
  const float* W1   = (const float*)d_in[2];
  const float* a1s  = (const float*)d_in[3];
  const float* a1d  = (const float*)d_in[4];
  const float* b1   = (const float*)d_in[5];
  const float* W2   = (const float*)d_in[6];
  const float* a2s  = (const float*)d_in[7];
  const float* a2d  = (const float*)d_in[8];
  const float* b2   = (const float*)d_in[9];
  float* out = (float*)d_out;

  char* ws = (char*)d_ws;
  size_t off = 0;
  auto alloc = [&](size_t bytes) {
    void* p = ws + off;
    off += bytes;
    off = (off + 255) & ~(size_t)255;
    return p;
  };

  ushort_t* h1   = (ushort_t*)alloc((size_t)N_NODES * 256 * 2);  // bf16
  ushort_t* a1b  = (ushort_t*)alloc((size_t)N_NODES * 256 * 2);  // bf16 relu(agg1+b1)
  ushort_t* h2   = (ushort_t*)alloc((size_t)N_NODES * 64 * 2);   // bf16
  ushort_t* W1t  = (ushort_t*)alloc((size_t)256 * 128 * 2);
  ushort_t* W2t  = (ushort_t*)alloc((size_t)64 * 256 * 2);
  float* asrc1   = (float*)alloc((size_t)N_NODES * 4);
  float* adst1   = (float*)alloc((size_t)N_NODES * 4);
  int*   deg     = (int*)alloc((size_t)N_NODES * 4);
  float* asrc2   = (float*)alloc((size_t)N_NODES * 4);
  float* adst2   = (float*)alloc((size_t)N_NODES * 4);
  int*   rowptr  = (int*)alloc((size_t)(N_NODES + 1) * 4);
  int*   fillp   = (int*)alloc((size_t)N_NODES * 4);
  int*   col     = (int*)alloc((size_t)E_TOT * 4);
  ull_t* state   = (ull_t*)alloc((size_t)SCAN_NB * 8);

  const int nodeBlocks4 = (N_NODES + 3) / 4;

  // 1. prep: zeros + weight transposes
  prep_kernel<<<1024, 256, 0, stream>>>(deg, asrc1, adst1, state, W1, W1t, W2, W2t);
  // 2. GEMM1 (+ fused alpha) merged with degree histogram
  hist_gemm1<<<GBM * 2 + EB, 256, 0, stream>>>(x, W1t, h1, a1s, a1d, asrc1, adst1, ei, deg);
  // 3. single-pass scan
  scan_lookback<<<SCAN_NB, 1024, 0, stream>>>(deg, state, rowptr, fillp);
  // 4. edge fill
  fill_kernel<<<EB, 256, 0, stream>>>(ei, fillp, col);
  // 5. layer-1 softmax+aggregate (+relu+bias -> bf16)
  fused_agg1<<<nodeBlocks4, 256, 0, stream>>>(h1, rowptr, col, asrc1, adst1, b1, a1b);
  // 6. GEMM2 (+ direct alpha)
  gemm2_kernel<<<GBM, 256, 0, stream>>>(a1b, W2t, h2, a2s, a2d, asrc2, adst2);
  // 7. layer-2 softmax+aggregate (+bias) -> out
  fused_agg2<<<nodeBlocks4, 256, 0, stream>>>(h2, rowptr, col, asrc2, adst2, b2, out);
}